// Round 4
// baseline (458.202 us; speedup 1.0000x reference)
//
#include <hip/hip_runtime.h>

// (S, L, H, P, K) = (512, 256, 768, 8, 8)
constexpr int S  = 512;
constexpr int L  = 256;
constexpr int H  = 768;
constexpr int P  = 8;
constexpr int K  = 8;
constexpr int H4 = H / 4;    // 192 float4 per token row
constexpr int PK = P * K;    // 64
constexpr int G  = 4;        // token groups per block (each 192 threads = 3 waves)
constexpr int NT = 192 * G;  // 768 threads = 12 waves

// One block per sequence, all 3 roles fused:
//   e_r[s,h] = sum_l wgt[r][l] * emb[s,l,h]
//   wgt[r][l] = sum_{(p,k): idx_r[s,p,k]==l} valid * pred[p]
//                 / (max(cnt_{r,p},1) * max(n_pred,1))
// Nonzero-weight tokens are compacted into a dense LDS list so the gather
// loop is branch-free (~44 iterations instead of 256 with ~83% skips), and
// each needed token row is fetched from HBM exactly once for all 3 roles.
//
// Bool-array layout (int32 vs uint8 vs float32) is detected at runtime from
// a 64-int probe of the mask array: values must be {0,1} (int32 mode) or
// {0,0x3F800000} (float32 mode); anything else means packed uint8 bools.
__global__ __launch_bounds__(NT) void srl_pool_fused(
    const float* __restrict__ emb,
    const int* __restrict__ idxV,  const int* __restrict__ mskV,
    const int* __restrict__ idxA0, const int* __restrict__ mskA0,
    const int* __restrict__ idxA1, const int* __restrict__ mskA1,
    const int* __restrict__ pred,
    float* __restrict__ out)
{
    const int s   = blockIdx.x;
    const int tid = threadIdx.x;

    __shared__ float  wgt[3][L];            // 3 KB  per-role per-token weight
    __shared__ float4 spack[L];             // 4 KB  {w0,w1,w2,token} compacted
    __shared__ int    scount;
    __shared__ float4 part[G - 1][3][H4];   // 27 KB partial accumulators

    // zero weight table (3*L <= NT covers it in one shot)
    if (tid < 3 * L) ((float*)wgt)[tid] = 0.0f;
    if (tid == 0) scount = 0;
    __syncthreads();

    // waves 0..2: one wave per role, one lane per (p,k) -> scatter coefs
    if (tid < 3 * 64) {
        const int role = tid >> 6;
        const int lane = tid & 63;
        const int p    = lane >> 3;

        const int* __restrict__ idx = (role == 0) ? idxV : (role == 1) ? idxA0 : idxA1;
        const int* __restrict__ msk = (role == 0) ? mskV : (role == 1) ? mskA0 : mskA1;

        // ---- bool layout detection (wave-uniform via ballot) ----
        unsigned probe = (unsigned)msk[lane];                 // 64 leading words
        unsigned long long b1 = __ballot(probe > 1u);
        unsigned long long b2 = __ballot(probe == 0x3F800000u);
        const int mode = (b1 == 0ull) ? 0 : (b1 == b2 ? 2 : 1); // 0=i32 1=u8 2=f32

        int iv = idx[s * PK + lane];

        bool mv, pd;
        if (mode == 0) {
            mv = msk[s * PK + lane] != 0;
            pd = pred[s * P + p]   != 0;
        } else if (mode == 1) {
            mv = ((const unsigned char*)msk)[s * PK + lane] != 0;
            pd = ((const unsigned char*)pred)[s * P + p]   != 0;
        } else {
            mv = ((const float*)msk)[s * PK + lane] != 0.0f;
            pd = ((const float*)pred)[s * P + p]   != 0.0f;
        }

        bool valid = mv && (iv < L);
        int  ic    = min(max(iv, 0), L - 1);

        // cnt_{role,p}: #valid within this 8-lane (p) group
        float cnt = valid ? 1.0f : 0.0f;
        cnt += __shfl_xor(cnt, 1);
        cnt += __shfl_xor(cnt, 2);
        cnt += __shfl_xor(cnt, 4);

        unsigned long long bp = __ballot(pd);    // each pred replicated on 8 lanes
        float n_pred = (float)(__popcll(bp) >> 3);

        if (valid && pd) {                       // n_pred>0 implied by pd; cnt>=1 by valid
            float coef = 1.0f / (fmaxf(cnt, 1.0f) * fmaxf(n_pred, 1.0f));
            atomicAdd(&wgt[role][ic], coef);     // duplicate indices: rare LDS collision
        }
    }
    __syncthreads();

    // compact nonzero tokens: one thread per token
    if (tid < L) {
        float w0 = wgt[0][tid], w1 = wgt[1][tid], w2 = wgt[2][tid];
        if (w0 != 0.0f || w1 != 0.0f || w2 != 0.0f) {
            int pos = atomicAdd(&scount, 1);
            spack[pos] = make_float4(w0, w1, w2, __int_as_float(tid));
        }
    }
    __syncthreads();

    const int g = tid / 192;     // token group (wave-aligned: 3 waves each)
    const int t = tid - g * 192; // float4 slice of H owned by this thread
    const int n = scount;

    const float4* __restrict__ emb4 = (const float4*)emb + (size_t)s * (L * H4);

    float4 a0 = make_float4(0.f, 0.f, 0.f, 0.f);
    float4 a1 = a0, a2 = a0;

    // dense branch-free gather: ~44/G iterations per group, loads pipeline
    #pragma unroll 4
    for (int j = g; j < n; j += G) {
        float4 wp = spack[j];                    // LDS broadcast
        int    l  = __float_as_int(wp.w);
        float4 v  = emb4[l * H4 + t];            // coalesced 3 KB row (once, 3 roles)
        a0.x += wp.x * v.x; a0.y += wp.x * v.y; a0.z += wp.x * v.z; a0.w += wp.x * v.w;
        a1.x += wp.y * v.x; a1.y += wp.y * v.y; a1.z += wp.y * v.z; a1.w += wp.y * v.w;
        a2.x += wp.z * v.x; a2.y += wp.z * v.y; a2.z += wp.z * v.z; a2.w += wp.z * v.w;
    }

    if (g > 0) {
        part[g - 1][0][t] = a0;
        part[g - 1][1][t] = a1;
        part[g - 1][2][t] = a2;
    }
    __syncthreads();

    if (g == 0) {
        #pragma unroll
        for (int q = 0; q < G - 1; ++q) {
            float4 b0 = part[q][0][t], b1 = part[q][1][t], b2 = part[q][2][t];
            a0.x += b0.x; a0.y += b0.y; a0.z += b0.z; a0.w += b0.w;
            a1.x += b1.x; a1.y += b1.y; a1.z += b1.z; a1.w += b1.w;
            a2.x += b2.x; a2.y += b2.y; a2.z += b2.z; a2.w += b2.w;
        }
        float4* __restrict__ o = (float4*)out;
        o[(0 * S + s) * H4 + t] = a0;   // e_V
        o[(1 * S + s) * H4 + t] = a1;   // e_A0
        o[(2 * S + s) * H4 + t] = a2;   // e_A1
    }
}

extern "C" void kernel_launch(void* const* d_in, const int* in_sizes, int n_in,
                              void* d_out, int out_size, void* d_ws, size_t ws_size,
                              hipStream_t stream) {
    const float* emb  = (const float*)d_in[0];
    const int* idxV   = (const int*)d_in[1];
    const int* mskV   = (const int*)d_in[2];
    const int* idxA0  = (const int*)d_in[3];
    const int* mskA0  = (const int*)d_in[4];
    const int* idxA1  = (const int*)d_in[5];
    const int* mskA1  = (const int*)d_in[6];
    const int* pred   = (const int*)d_in[7];

    srl_pool_fused<<<dim3(S), NT, 0, stream>>>(
        emb, idxV, mskV, idxA0, mskA0, idxA1, mskA1, pred, (float*)d_out);
}